// Round 11
// baseline (5776.233 us; speedup 1.0000x reference)
//
#include <hip/hip_runtime.h>

#define NWG 256
#define NT  512
#define ROWS 8        // rows per WG (row slice)
#define JPT 8         // cols per thread (row slice)
#define CPW 16        // cols per WG (col slice)
#define RPT 64        // rows per thread (col slice)
#define NDIM 4096
#define MROWS 2048
#define N_ADMM 30
#define N_CG 15

typedef unsigned long long ull;
typedef float f32x4 __attribute__((ext_vector_type(4)));

static_assert(NWG * ROWS == MROWS, "row partition");
static_assert(NT * JPT == NDIM, "col partition");
static_assert(NWG * CPW == NDIM, "col-slice partition");
static_assert(32 * RPT == MROWS, "col-slice rows");

__device__ __forceinline__ float wred64(float v) {
#pragma unroll
  for (int m = 32; m > 0; m >>= 1) v += __shfl_xor(v, m, 64);
  return v;
}
__device__ __forceinline__ float sum8(float v) {
  v += __shfl_xor(v, 1, 64); v += __shfl_xor(v, 2, 64); v += __shfl_xor(v, 4, 64);
  return v;
}
__device__ __forceinline__ float sum16(float v) {
  v += __shfl_xor(v, 1, 64); v += __shfl_xor(v, 2, 64);
  v += __shfl_xor(v, 4, 64); v += __shfl_xor(v, 8, 64);
  return v;
}
// writers: relaxed agent atomics (LLC-direct, no L2 alloc); readers: nontemporal
// (no-allocate, LLC-served). No exchange line ever lives in L1/L2 -> fence-free.
__device__ __forceinline__ void st64(ull* p, ull v) {
  __hip_atomic_store(p, v, __ATOMIC_RELAXED, __HIP_MEMORY_SCOPE_AGENT);
}
__device__ __forceinline__ ull ld64(const ull* p) {
  return __hip_atomic_load(p, __ATOMIC_RELAXED, __HIP_MEMORY_SCOPE_AGENT);
}
__device__ __forceinline__ f32x4 ntf4(const float* p) {
  return __builtin_nontemporal_load((const f32x4*)p);
}
__device__ __forceinline__ ull pk2(float a, float b) {
  return ((ull)__float_as_uint(b) << 32) | (ull)__float_as_uint(a);
}

// -------- workspace layout (NO overlaps; R10's bug was bank1/z_g aliasing) ----
#define WS_KILL   128
#define WS_BANK0  8192      // 256 slots x 64B = 16384 -> ends 24576
#define WS_BANK1  24576     // 16384 -> ends 40960
#define WS_Z      49152     // 4096 f32 = 16384 -> ends 65536
#define WS_XT     65536     // 16384 -> ends 81920
#define WS_T      81920     // 2048 f32 = 8192 -> ends 90112
#define WS_U      90112     // 8192 -> ends 98304

__global__ __launch_bounds__(NT, 2)
void admm_lp_kernel(const float* __restrict__ A, const float* __restrict__ cvec,
                    const float* __restrict__ lbv, const float* __restrict__ ubv,
                    const float* __restrict__ dvec, const float* __restrict__ evec,
                    const float* __restrict__ gcp, const float* __restrict__ gbp,
                    const float* __restrict__ rhop, const float* __restrict__ sigp,
                    const float* __restrict__ alp,
                    float* __restrict__ out, unsigned char* __restrict__ ws)
{
  const int tid = threadIdx.x;
  const int w = blockIdx.x;
  const int wv = tid >> 6;         // wave index 0..7
  const int lane = tid & 63;
  const int j0 = tid * JPT;        // row-slice column base
  const int row0 = w * ROWS;
  const int g = tid >> 4;          // col-slice row group 0..31
  const int l = tid & 15;          // col within WG's 16-col slice

  unsigned* kill = (unsigned*)(ws + WS_KILL);
  // PING-PONG flag banks: bank G&1 holds generation-G publishes. A slot is
  // only overwritten at G+2, which cannot happen while any WG still polls G
  // (publish(G+1) is __syncthreads-ordered after that WG's reads of gen G).
  ull* fbank[2] = { (ull*)(ws + WS_BANK0), (ull*)(ws + WS_BANK1) };
  float* z_g  = (float*)(ws + WS_Z);
  float* xt_g = (float*)(ws + WS_XT);
  float* t_g  = (float*)(ws + WS_T);
  float* u_g  = (float*)(ws + WS_U);
  ull* z64 = (ull*)z_g; ull* xt64 = (ull*)xt_g; ull* t64 = (ull*)t_g; ull* u64 = (ull*)u_g;

  __shared__ float s_scal[6];
  __shared__ float dred[8][ROWS];
  __shared__ float sredA[32][16];
  __shared__ float sredB[32][16];
  __shared__ int s_dead;

  float areg[ROWS][JPT];   // row slice of A
  float acol[RPT];         // col slice of A (rows g*64.., col w*16+l)

  unsigned gen = 0;

  // per-wave producer wait: wave v needs flags[v*32 .. v*32+31] >= G (bank G&1)
  auto wait_prod = [&](unsigned G) {
    if (s_dead) return;
    ull* fp = &fbank[G & 1][(size_t)(wv * 32 + (lane & 31)) * 8];
    int spin = 0;
    for (;;) {
      ull v = ld64(fp);
      if (__all((unsigned)(v >> 32) >= G)) break;
      __builtin_amdgcn_s_sleep(1);
      if ((++spin & 127) == 0) {
        if (__hip_atomic_load(kill, __ATOMIC_RELAXED, __HIP_MEMORY_SCOPE_AGENT) != 0u ||
            spin > 300000) {
          s_dead = 1;
          __hip_atomic_store(kill, 1u, __ATOMIC_RELAXED, __HIP_MEMORY_SCOPE_AGENT);
          break;
        }
      }
    }
    asm volatile("" ::: "memory");
    __builtin_amdgcn_sched_barrier(0);
  };

  // wave-0 only: wait all 256 flags of bank G&1 >= G, return sum of partials
  auto poll_all = [&](unsigned G) -> float {
    ull v0 = 0, v1 = 0, v2 = 0, v3 = 0;
    if (!s_dead) {
      ull* fb = fbank[G & 1];
      ull* f0 = &fb[(size_t)(lane * 4 + 0) * 8];
      ull* f1 = &fb[(size_t)(lane * 4 + 1) * 8];
      ull* f2 = &fb[(size_t)(lane * 4 + 2) * 8];
      ull* f3 = &fb[(size_t)(lane * 4 + 3) * 8];
      int spin = 0;
      for (;;) {
        v0 = ld64(f0); v1 = ld64(f1); v2 = ld64(f2); v3 = ld64(f3);
        bool ok = ((unsigned)(v0 >> 32) >= G) && ((unsigned)(v1 >> 32) >= G) &&
                  ((unsigned)(v2 >> 32) >= G) && ((unsigned)(v3 >> 32) >= G);
        if (__all(ok)) break;
        __builtin_amdgcn_s_sleep(1);
        if ((++spin & 127) == 0) {
          if (__hip_atomic_load(kill, __ATOMIC_RELAXED, __HIP_MEMORY_SCOPE_AGENT) != 0u ||
              spin > 300000) {
            s_dead = 1;
            __hip_atomic_store(kill, 1u, __ATOMIC_RELAXED, __HIP_MEMORY_SCOPE_AGENT);
            break;
          }
        }
      }
    }
    asm volatile("" ::: "memory");
    __builtin_amdgcn_sched_barrier(0);
    float s = __uint_as_float((unsigned)(v0 & 0xffffffffu))
            + __uint_as_float((unsigned)(v1 & 0xffffffffu))
            + __uint_as_float((unsigned)(v2 & 0xffffffffu))
            + __uint_as_float((unsigned)(v3 & 0xffffffffu));
    return wred64(s);
  };

  // wave-0 only: drain data stores, then flag {gen+1, partial} into bank (gen+1)&1
  auto publish = [&](float partial) {
    asm volatile("s_waitcnt vmcnt(0)" ::: "memory");
    __builtin_amdgcn_sched_barrier(0);
    if (lane == 0 && !s_dead)
      st64(&fbank[(gen + 1) & 1][(size_t)w * 8],
           ((ull)(gen + 1) << 32) | (ull)__float_as_uint(partial));
  };

  // ---------------- prologue ----------------------------------------------------
  if (tid == 0) {
    s_scal[0] = sigp[0]; s_scal[1] = rhop[0]; s_scal[2] = alp[0];
    s_scal[3] = gcp[0];  s_scal[4] = gbp[0];
    s_dead = 0;
  }
  {
#pragma unroll
    for (int r = 0; r < ROWS; ++r) {
      const float* ap = A + (size_t)(row0 + r) * NDIM + j0;
      const float4 a0 = *(const float4*)(ap);
      const float4 a1 = *(const float4*)(ap + 4);
      areg[r][0] = a0.x; areg[r][1] = a0.y; areg[r][2] = a0.z; areg[r][3] = a0.w;
      areg[r][4] = a1.x; areg[r][5] = a1.y; areg[r][6] = a1.z; areg[r][7] = a1.w;
    }
    float cn = 0.f;
#pragma unroll
    for (int r = 0; r < RPT; ++r) {
      acol[r] = A[(size_t)(g * RPT + r) * NDIM + w * CPW + l];
      cn += acol[r] * acol[r];
    }
    sredA[g][l] = cn;
  }
  __syncthreads();

  const float sig = s_scal[0], rho = s_scal[1], al = s_scal[2];

  // wave-0 register state (low lanes)
  float f_cs = 0.f, f_Md = 1.f, f_rl = 0.f, f_pch = 0.f, f_xtl = 0.f, f_xa = 0.f;
  float f_zown = 0.f, f_trow = 0.f, f_zb = 0.f, f_yb = 0.f, f_lbs = 0.f, f_ubs = 0.f;
  float rz_cur = 1.f, gbv = 1.f;

  if (wv == 0) {
    gbv = s_scal[4];
    if (lane < 8) {
      const float ee = evec[row0 + lane];
      f_lbs = gbv * ee * lbv[row0 + lane];
      f_ubs = gbv * ee * ubv[row0 + lane];
    }
    if (lane < 16) {
      f_cs = s_scal[3] * dvec[w * 16 + lane] * cvec[w * 16 + lane];
      float S = 0.f;
#pragma unroll
      for (int q = 0; q < 32; ++q) S += sredA[q][lane];
      f_Md = sig + rho * S;
      f_rl = -f_cs;
      f_zown = f_rl / f_Md;
    }
    float rzp = (lane < 16) ? f_rl * f_zown : 0.f;
    rzp = sum16(rzp);
    float a0 = __shfl(f_zown, (lane & 7) * 2, 64);
    float b0 = __shfl(f_zown, (lane & 7) * 2 + 1, 64);
    if (lane < 8) st64(&z64[(size_t)w * 8 + lane], pk2(a0, b0));
    publish(rzp);    // gen 1: z + rz0 partial
  }
  ++gen;             // gen = 1

  // ---------------- main loop ----------------------------------------------------
  for (int admm = 0; admm < N_ADMM; ++admm) {
    for (int cg = 0; cg < N_CG; ++cg) {
      // ---- P1: Az rows; t = Az + beta*t_old; publish t + pKp partial -----------
      {
        wait_prod(gen);                       // z producers
        const f32x4 za = ntf4(z_g + j0);
        const f32x4 zc = ntf4(z_g + j0 + 4);
        const float zl[JPT] = {za.x, za.y, za.z, za.w, zc.x, zc.y, zc.z, zc.w};
        float dp[ROWS];
#pragma unroll
        for (int r = 0; r < ROWS; ++r) {
          float s = 0.f;
#pragma unroll
          for (int k = 0; k < JPT; ++k) s += areg[r][k] * zl[k];
          dp[r] = s;
        }
#pragma unroll
        for (int r = 0; r < ROWS; ++r) {
          const float t = wred64(dp[r]);
          if (lane == 0) dred[wv][r] = t;
        }
        __syncthreads();
        if (wv == 0) {
          const float rz_new = poll_all(gen); // rz_k (overlapped: usually 1 round)
          const float beta = (cg == 0) ? 0.f : rz_new / rz_cur;
          rz_cur = rz_new;
          float az = 0.f;
          if (lane < 8) {
#pragma unroll
            for (int q = 0; q < 8; ++q) az += dred[q][lane];
          }
          f_trow = az + beta * f_trow;        // t-recurrence (A(z+bp) = Az + b*Ap)
          f_pch  = f_zown + beta * f_pch;     // p at own 16 cols
          float st2 = (lane < 8) ? f_trow * f_trow : 0.f;
          st2 = sum8(st2);
          float sp2 = (lane < 16) ? f_pch * f_pch : 0.f;
          sp2 = sum16(sp2);
          const float part = rho * st2 + sig * sp2;
          float a0 = __shfl(f_trow, (lane & 3) * 2, 64);
          float b0 = __shfl(f_trow, (lane & 3) * 2 + 1, 64);
          if (lane < 4) st64(&t64[(size_t)w * 4 + lane], pk2(a0, b0));
          publish(part);
        }
        ++gen;
      }
      // ---- P2: u = A^T t cols; alpha; r/x/z updates; publish z + rz partial ----
      {
        wait_prod(gen);                       // t producers
        float up = 0.f;
#pragma unroll
        for (int r4 = 0; r4 < RPT / 4; ++r4) {
          const f32x4 tv = ntf4(t_g + g * RPT + r4 * 4);
          up += tv.x * acol[r4 * 4 + 0] + tv.y * acol[r4 * 4 + 1]
              + tv.z * acol[r4 * 4 + 2] + tv.w * acol[r4 * 4 + 3];
        }
        sredA[g][l] = up;
        __syncthreads();
        if (wv == 0) {
          const float pkp = poll_all(gen);
          const float alpha = rz_cur / pkp;
          float S = 0.f;
          if (lane < 16) {
#pragma unroll
            for (int q = 0; q < 32; ++q) S += sredA[q][lane];
          }
          const float Kp = rho * S + sig * f_pch;
          const float rn = f_rl - alpha * Kp;
          f_rl = rn;
          f_xtl += alpha * f_pch;
          f_zown = rn / f_Md;
          float rzp = (lane < 16) ? rn * f_zown : 0.f;
          rzp = sum16(rzp);
          float a0 = __shfl(f_zown, (lane & 7) * 2, 64);
          float b0 = __shfl(f_zown, (lane & 7) * 2 + 1, 64);
          if (lane < 8) st64(&z64[(size_t)w * 8 + lane], pk2(a0, b0));
          if (cg == N_CG - 1) {
            float c0 = __shfl(f_xtl, (lane & 7) * 2, 64);
            float d0 = __shfl(f_xtl, (lane & 7) * 2 + 1, 64);
            if (lane < 8) st64(&xt64[(size_t)w * 8 + lane], pk2(c0, d0));
          }
          publish(rzp);
        }
        ++gen;
      }
    }
    if (admm < N_ADMM - 1) {
      // ---- A': ztilde = A xt rows; z/y/x updates; publish t(raw), u ------------
      {
        wait_prod(gen);                       // xt producers
        const f32x4 xv0 = ntf4(xt_g + j0);
        const f32x4 xv1 = ntf4(xt_g + j0 + 4);
        const float xl[JPT] = {xv0.x, xv0.y, xv0.z, xv0.w, xv1.x, xv1.y, xv1.z, xv1.w};
        float dp[ROWS];
#pragma unroll
        for (int r = 0; r < ROWS; ++r) {
          float s = 0.f;
#pragma unroll
          for (int k = 0; k < JPT; ++k) s += areg[r][k] * xl[k];
          dp[r] = s;
        }
#pragma unroll
        for (int r = 0; r < ROWS; ++r) {
          const float t = wred64(dp[r]);
          if (lane == 0) dred[wv][r] = t;
        }
        __syncthreads();
        if (wv == 0) {
          (void)poll_all(gen);                // WAR guard before t_g/u_g overwrite
          float ztr = 0.f, urow = 0.f;
          if (lane < 8) {
#pragma unroll
            for (int q = 0; q < 8; ++q) ztr += dred[q][lane];
            const float zt = al * ztr + (1.f - al) * f_zb;
            float zn = fminf(fmaxf(zt + f_yb / rho, f_lbs), f_ubs);
            const float yn = f_yb + rho * (zt - zn);
            f_zb = zn; f_yb = yn;
            urow = rho * zn - yn;
          }
          f_xa = al * f_xtl + (1.f - al) * f_xa;   // x at own 16 cols
          float ta = __shfl(ztr,  (lane & 3) * 2, 64);
          float tb = __shfl(ztr,  (lane & 3) * 2 + 1, 64);
          float ua = __shfl(urow, (lane & 3) * 2, 64);
          float ub = __shfl(urow, (lane & 3) * 2 + 1, 64);
          if (lane < 4) {
            st64(&t64[(size_t)w * 4 + lane], pk2(ta, tb));
            st64(&u64[(size_t)w * 4 + lane], pk2(ua, ub));
          }
          publish(0.f);
        }
        ++gen;
      }
      // ---- B: right = sig*x - c + A^T u; r0 = right - Kop(xt); publish z -------
      {
        wait_prod(gen);                       // t,u producers
        float pk = 0.f, pr = 0.f;
#pragma unroll
        for (int r4 = 0; r4 < RPT / 4; ++r4) {
          const f32x4 tv = ntf4(t_g + g * RPT + r4 * 4);
          const f32x4 uv = ntf4(u_g + g * RPT + r4 * 4);
          pk += tv.x * acol[r4 * 4 + 0] + tv.y * acol[r4 * 4 + 1]
              + tv.z * acol[r4 * 4 + 2] + tv.w * acol[r4 * 4 + 3];
          pr += uv.x * acol[r4 * 4 + 0] + uv.y * acol[r4 * 4 + 1]
              + uv.z * acol[r4 * 4 + 2] + uv.w * acol[r4 * 4 + 3];
        }
        sredA[g][l] = pk; sredB[g][l] = pr;
        __syncthreads();
        if (wv == 0) {
          (void)poll_all(gen);                // WAR guard before z overwrite
          float SK = 0.f, SR = 0.f;
          if (lane < 16) {
#pragma unroll
            for (int q = 0; q < 32; ++q) { SK += sredA[q][lane]; SR += sredB[q][lane]; }
          }
          const float right = sig * f_xa - f_cs + SR;
          const float Kx = rho * SK + sig * f_xtl;
          const float r0 = right - Kx;
          f_rl = r0;
          f_zown = r0 / f_Md;
          float rzp = (lane < 16) ? r0 * f_zown : 0.f;
          rzp = sum16(rzp);
          float a0 = __shfl(f_zown, (lane & 7) * 2, 64);
          float b0 = __shfl(f_zown, (lane & 7) * 2 + 1, 64);
          if (lane < 8) st64(&z64[(size_t)w * 8 + lane], pk2(a0, b0));
          publish(rzp);
        }
        ++gen;
      }
    }
  }
  // ---------------- final: out = (al*xt + (1-al)*x) * d / gb ---------------------
  if (wv == 0 && lane < 16) {
    const float xf = al * f_xtl + (1.f - al) * f_xa;
    out[w * 16 + lane] = xf * dvec[w * 16 + lane] / gbv;
  }
}

extern "C" void kernel_launch(void* const* d_in, const int* in_sizes, int n_in,
                              void* d_out, int out_size, void* d_ws, size_t ws_size,
                              hipStream_t stream) {
  const float* A   = (const float*)d_in[0];
  const float* c   = (const float*)d_in[1];
  const float* lb  = (const float*)d_in[2];
  const float* ub  = (const float*)d_in[3];
  const float* dv  = (const float*)d_in[4];
  const float* ev  = (const float*)d_in[5];
  const float* gc  = (const float*)d_in[6];
  const float* gb  = (const float*)d_in[7];
  const float* rho = (const float*)d_in[8];
  const float* sg  = (const float*)d_in[9];
  const float* al  = (const float*)d_in[10];
  float* out = (float*)d_out;
  unsigned char* ws = (unsigned char*)d_ws;

  // zero kill + both flag banks (first 40960 B; data buffers start at 49152)
  (void)hipMemsetAsync(d_ws, 0, 40960, stream);

  admm_lp_kernel<<<dim3(NWG), dim3(NT), 0, stream>>>(
      A, c, lb, ub, dv, ev, gc, gb, rho, sg, al, out, ws);
}

// Round 12
// 5514.904 us; speedup vs baseline: 1.0474x; 1.0474x over previous
//
#include <hip/hip_runtime.h>

#define NWG 256
#define NT  512
#define ROWS 8        // rows per WG (row slice)
#define JPT 8         // cols per thread (row slice)
#define CPW 16        // cols per WG (col slice)
#define RPT 64        // rows per thread (col slice)
#define NDIM 4096
#define MROWS 2048
#define N_ADMM 30
#define N_CG 15

typedef unsigned long long ull;
typedef float f32x4 __attribute__((ext_vector_type(4)));

static_assert(NWG * ROWS == MROWS, "row partition");
static_assert(NT * JPT == NDIM, "col partition");
static_assert(NWG * CPW == NDIM, "col-slice partition");
static_assert(32 * RPT == MROWS, "col-slice rows");

__device__ __forceinline__ float wred64(float v) {
#pragma unroll
  for (int m = 32; m > 0; m >>= 1) v += __shfl_xor(v, m, 64);
  return v;
}
__device__ __forceinline__ float sum8(float v) {
  v += __shfl_xor(v, 1, 64); v += __shfl_xor(v, 2, 64); v += __shfl_xor(v, 4, 64);
  return v;
}
__device__ __forceinline__ float sum16(float v) {
  v += __shfl_xor(v, 1, 64); v += __shfl_xor(v, 2, 64);
  v += __shfl_xor(v, 4, 64); v += __shfl_xor(v, 8, 64);
  return v;
}
// writers: relaxed agent atomics (LLC-direct, no L2 alloc); readers: nontemporal
// (no-allocate, LLC-served). No exchange line ever lives in L1/L2 -> fence-free.
__device__ __forceinline__ void st64(ull* p, ull v) {
  __hip_atomic_store(p, v, __ATOMIC_RELAXED, __HIP_MEMORY_SCOPE_AGENT);
}
__device__ __forceinline__ ull ld64(const ull* p) {
  return __hip_atomic_load(p, __ATOMIC_RELAXED, __HIP_MEMORY_SCOPE_AGENT);
}
__device__ __forceinline__ f32x4 ntf4(const float* p) {
  return __builtin_nontemporal_load((const f32x4*)p);
}
__device__ __forceinline__ ull pk2(float a, float b) {
  return ((ull)__float_as_uint(b) << 32) | (ull)__float_as_uint(a);
}

// -------- workspace layout (no overlaps) --------------------------------------
#define WS_KILL   128
#define WS_BANK0  8192      // L0: 256 slots x 64B -> ends 24576
#define WS_BANK1  24576     // -> ends 40960
#define WS_L1B0   40960     // L1: 8 slots x 64B  -> ends 41472
#define WS_L1B1   43008     // -> ends 43520
#define WS_Z      49152     // 16384 -> ends 65536
#define WS_XT     65536     // 16384 -> ends 81920
#define WS_T      81920     // 8192  -> ends 90112
#define WS_U      90112     // 8192  -> ends 98304

__global__ __launch_bounds__(NT, 2)
void admm_lp_kernel(const float* __restrict__ A, const float* __restrict__ cvec,
                    const float* __restrict__ lbv, const float* __restrict__ ubv,
                    const float* __restrict__ dvec, const float* __restrict__ evec,
                    const float* __restrict__ gcp, const float* __restrict__ gbp,
                    const float* __restrict__ rhop, const float* __restrict__ sigp,
                    const float* __restrict__ alp,
                    float* __restrict__ out, unsigned char* __restrict__ ws)
{
  const int tid = threadIdx.x;
  const int w = blockIdx.x;
  const int wv = tid >> 6;         // wave index 0..7
  const int lane = tid & 63;
  const int j0 = tid * JPT;        // row-slice column base
  const int row0 = w * ROWS;
  const int g = tid >> 4;          // col-slice row group 0..31
  const int l = tid & 15;          // col within WG's 16-col slice

  unsigned* kill = (unsigned*)(ws + WS_KILL);
  // Two-level ping-pong flag tree. L0: one 64B slot per WG {gen, partial}.
  // L1: one 64B slot per producer-group (8 groups of 32 WGs) {gen, groupsum},
  // published by the aggregator wave (WG k, wave k aggregates group k -- which
  // is exactly that wave's own data-dependency group). All other waves gate on
  // a single L1 line. Wave 0's global scalar = sum of the 8 L1 partials.
  // Bank G&1 holds generation G; overwrite at G+2 is ordered after every
  // reader's G-read via the L1[G+1] dependency chain (WAR-safe).
  ull* fbank[2]  = { (ull*)(ws + WS_BANK0), (ull*)(ws + WS_BANK1) };
  ull* l1bank[2] = { (ull*)(ws + WS_L1B0),  (ull*)(ws + WS_L1B1)  };
  float* z_g  = (float*)(ws + WS_Z);
  float* xt_g = (float*)(ws + WS_XT);
  float* t_g  = (float*)(ws + WS_T);
  float* u_g  = (float*)(ws + WS_U);
  ull* z64 = (ull*)z_g; ull* xt64 = (ull*)xt_g; ull* t64 = (ull*)t_g; ull* u64 = (ull*)u_g;

  __shared__ float s_scal[6];
  __shared__ float dred[8][ROWS];
  __shared__ float sredA[32][16];
  __shared__ float sredB[32][16];
  __shared__ int s_dead;

  float areg[ROWS][JPT];   // row slice of A
  float acol[RPT];         // col slice of A (rows g*64.., col w*16+l)

  unsigned gen = 0;

  // data gate for this wave's producer group (aggregating if it's the owner)
  auto gate = [&](unsigned G) {
    if (s_dead) return;
    ull* l0 = fbank[G & 1];
    ull* l1 = l1bank[G & 1];
    if (w < 8 && wv == w) {
      // aggregator: poll own group's 32 L0 lines, sum partials, publish L1[wv]
      ull* fp = &l0[(size_t)(wv * 32 + (lane & 31)) * 8];
      ull v;
      int spin = 0;
      for (;;) {
        v = ld64(fp);
        if (__all((unsigned)(v >> 32) >= G)) break;
        __builtin_amdgcn_s_sleep(1);
        if ((++spin & 127) == 0) {
          if (__hip_atomic_load(kill, __ATOMIC_RELAXED, __HIP_MEMORY_SCOPE_AGENT) != 0u ||
              spin > 300000) {
            s_dead = 1;
            __hip_atomic_store(kill, 1u, __ATOMIC_RELAXED, __HIP_MEMORY_SCOPE_AGENT);
            break;
          }
        }
      }
      float pv = (lane < 32) ? __uint_as_float((unsigned)(v & 0xffffffffu)) : 0.f;
      float s = wred64(pv);
      if (lane == 0 && !s_dead)
        st64(&l1[(size_t)wv * 8], ((ull)G << 32) | (ull)__float_as_uint(s));
    } else {
      ull* fp = &l1[(size_t)wv * 8];
      int spin = 0;
      for (;;) {
        ull v = ld64(fp);
        if (__all((unsigned)(v >> 32) >= G)) break;
        __builtin_amdgcn_s_sleep(1);
        if ((++spin & 127) == 0) {
          if (__hip_atomic_load(kill, __ATOMIC_RELAXED, __HIP_MEMORY_SCOPE_AGENT) != 0u ||
              spin > 300000) {
            s_dead = 1;
            __hip_atomic_store(kill, 1u, __ATOMIC_RELAXED, __HIP_MEMORY_SCOPE_AGENT);
            break;
          }
        }
      }
    }
    asm volatile("" ::: "memory");
    __builtin_amdgcn_sched_barrier(0);
  };

  // wave-0 only: wait all 8 L1 slots >= G, return global sum of group partials
  auto global_sum = [&](unsigned G) -> float {
    ull v = 0;
    if (!s_dead) {
      ull* fp = &l1bank[G & 1][(size_t)(lane & 7) * 8];
      int spin = 0;
      for (;;) {
        v = ld64(fp);
        if (__all((unsigned)(v >> 32) >= G)) break;
        __builtin_amdgcn_s_sleep(1);
        if ((++spin & 127) == 0) {
          if (__hip_atomic_load(kill, __ATOMIC_RELAXED, __HIP_MEMORY_SCOPE_AGENT) != 0u ||
              spin > 300000) {
            s_dead = 1;
            __hip_atomic_store(kill, 1u, __ATOMIC_RELAXED, __HIP_MEMORY_SCOPE_AGENT);
            break;
          }
        }
      }
    }
    asm volatile("" ::: "memory");
    __builtin_amdgcn_sched_barrier(0);
    float pv = (lane < 8) ? __uint_as_float((unsigned)(v & 0xffffffffu)) : 0.f;
    return wred64(pv);
  };

  // wave-0 only: drain data stores, then L0 flag {gen+1, partial}
  auto publish = [&](float partial) {
    asm volatile("s_waitcnt vmcnt(0)" ::: "memory");
    __builtin_amdgcn_sched_barrier(0);
    if (lane == 0 && !s_dead)
      st64(&fbank[(gen + 1) & 1][(size_t)w * 8],
           ((ull)(gen + 1) << 32) | (ull)__float_as_uint(partial));
  };

  // ---------------- prologue ----------------------------------------------------
  if (tid == 0) {
    s_scal[0] = sigp[0]; s_scal[1] = rhop[0]; s_scal[2] = alp[0];
    s_scal[3] = gcp[0];  s_scal[4] = gbp[0];
    s_dead = 0;
  }
  {
#pragma unroll
    for (int r = 0; r < ROWS; ++r) {
      const float* ap = A + (size_t)(row0 + r) * NDIM + j0;
      const float4 a0 = *(const float4*)(ap);
      const float4 a1 = *(const float4*)(ap + 4);
      areg[r][0] = a0.x; areg[r][1] = a0.y; areg[r][2] = a0.z; areg[r][3] = a0.w;
      areg[r][4] = a1.x; areg[r][5] = a1.y; areg[r][6] = a1.z; areg[r][7] = a1.w;
    }
    float cn = 0.f;
#pragma unroll
    for (int r = 0; r < RPT; ++r) {
      acol[r] = A[(size_t)(g * RPT + r) * NDIM + w * CPW + l];
      cn += acol[r] * acol[r];
    }
    sredA[g][l] = cn;
  }
  __syncthreads();

  const float sig = s_scal[0], rho = s_scal[1], al = s_scal[2];

  // wave-0 register state (low lanes)
  float f_cs = 0.f, f_Md = 1.f, f_rl = 0.f, f_pch = 0.f, f_xtl = 0.f, f_xa = 0.f;
  float f_zown = 0.f, f_trow = 0.f, f_zb = 0.f, f_yb = 0.f, f_lbs = 0.f, f_ubs = 0.f;
  float rz_cur = 1.f, gbv = 1.f;

  if (wv == 0) {
    gbv = s_scal[4];
    if (lane < 8) {
      const float ee = evec[row0 + lane];
      f_lbs = gbv * ee * lbv[row0 + lane];
      f_ubs = gbv * ee * ubv[row0 + lane];
    }
    if (lane < 16) {
      f_cs = s_scal[3] * dvec[w * 16 + lane] * cvec[w * 16 + lane];
      float S = 0.f;
#pragma unroll
      for (int q = 0; q < 32; ++q) S += sredA[q][lane];
      f_Md = sig + rho * S;
      f_rl = -f_cs;
      f_zown = f_rl / f_Md;
    }
    float rzp = (lane < 16) ? f_rl * f_zown : 0.f;
    rzp = sum16(rzp);
    float a0 = __shfl(f_zown, (lane & 7) * 2, 64);
    float b0 = __shfl(f_zown, (lane & 7) * 2 + 1, 64);
    if (lane < 8) st64(&z64[(size_t)w * 8 + lane], pk2(a0, b0));
    publish(rzp);    // gen 1: z + rz0 partial
  }
  ++gen;             // gen = 1

  // ---------------- main loop ----------------------------------------------------
  for (int admm = 0; admm < N_ADMM; ++admm) {
    for (int cg = 0; cg < N_CG; ++cg) {
      // ---- P1: Az rows; t = Az + beta*t_old; publish t + pKp partial -----------
      {
        gate(gen);                            // z producers (group wv)
        const f32x4 za = ntf4(z_g + j0);
        const f32x4 zc = ntf4(z_g + j0 + 4);
        const float zl[JPT] = {za.x, za.y, za.z, za.w, zc.x, zc.y, zc.z, zc.w};
        float dp[ROWS];
#pragma unroll
        for (int r = 0; r < ROWS; ++r) {
          float s = 0.f;
#pragma unroll
          for (int k = 0; k < JPT; ++k) s += areg[r][k] * zl[k];
          dp[r] = s;
        }
#pragma unroll
        for (int r = 0; r < ROWS; ++r) {
          const float t = wred64(dp[r]);
          if (lane == 0) dred[wv][r] = t;
        }
        __syncthreads();
        if (wv == 0) {
          const float rz_new = global_sum(gen);
          const float beta = (cg == 0) ? 0.f : rz_new / rz_cur;
          rz_cur = rz_new;
          float az = 0.f;
          if (lane < 8) {
#pragma unroll
            for (int q = 0; q < 8; ++q) az += dred[q][lane];
          }
          f_trow = az + beta * f_trow;        // t-recurrence (A(z+bp) = Az + b*Ap)
          f_pch  = f_zown + beta * f_pch;     // p at own 16 cols
          float st2 = (lane < 8) ? f_trow * f_trow : 0.f;
          st2 = sum8(st2);
          float sp2 = (lane < 16) ? f_pch * f_pch : 0.f;
          sp2 = sum16(sp2);
          const float part = rho * st2 + sig * sp2;
          float a0 = __shfl(f_trow, (lane & 3) * 2, 64);
          float b0 = __shfl(f_trow, (lane & 3) * 2 + 1, 64);
          if (lane < 4) st64(&t64[(size_t)w * 4 + lane], pk2(a0, b0));
          publish(part);
        }
        ++gen;
      }
      // ---- P2: u = A^T t cols; alpha; r/x/z updates; publish z + rz partial ----
      {
        gate(gen);                            // t producers (group wv)
        float up = 0.f;
#pragma unroll
        for (int r4 = 0; r4 < RPT / 4; ++r4) {
          const f32x4 tv = ntf4(t_g + g * RPT + r4 * 4);
          up += tv.x * acol[r4 * 4 + 0] + tv.y * acol[r4 * 4 + 1]
              + tv.z * acol[r4 * 4 + 2] + tv.w * acol[r4 * 4 + 3];
        }
        sredA[g][l] = up;
        __syncthreads();
        if (wv == 0) {
          const float pkp = global_sum(gen);
          const float alpha = rz_cur / pkp;
          float S = 0.f;
          if (lane < 16) {
#pragma unroll
            for (int q = 0; q < 32; ++q) S += sredA[q][lane];
          }
          const float Kp = rho * S + sig * f_pch;
          const float rn = f_rl - alpha * Kp;
          f_rl = rn;
          f_xtl += alpha * f_pch;
          f_zown = rn / f_Md;
          float rzp = (lane < 16) ? rn * f_zown : 0.f;
          rzp = sum16(rzp);
          float a0 = __shfl(f_zown, (lane & 7) * 2, 64);
          float b0 = __shfl(f_zown, (lane & 7) * 2 + 1, 64);
          if (lane < 8) st64(&z64[(size_t)w * 8 + lane], pk2(a0, b0));
          if (cg == N_CG - 1) {
            float c0 = __shfl(f_xtl, (lane & 7) * 2, 64);
            float d0 = __shfl(f_xtl, (lane & 7) * 2 + 1, 64);
            if (lane < 8) st64(&xt64[(size_t)w * 8 + lane], pk2(c0, d0));
          }
          publish(rzp);
        }
        ++gen;
      }
    }
    if (admm < N_ADMM - 1) {
      // ---- A': ztilde = A xt rows; z/y/x updates; publish t(raw), u ------------
      {
        gate(gen);                            // xt producers
        const f32x4 xv0 = ntf4(xt_g + j0);
        const f32x4 xv1 = ntf4(xt_g + j0 + 4);
        const float xl[JPT] = {xv0.x, xv0.y, xv0.z, xv0.w, xv1.x, xv1.y, xv1.z, xv1.w};
        float dp[ROWS];
#pragma unroll
        for (int r = 0; r < ROWS; ++r) {
          float s = 0.f;
#pragma unroll
          for (int k = 0; k < JPT; ++k) s += areg[r][k] * xl[k];
          dp[r] = s;
        }
#pragma unroll
        for (int r = 0; r < ROWS; ++r) {
          const float t = wred64(dp[r]);
          if (lane == 0) dred[wv][r] = t;
        }
        __syncthreads();
        if (wv == 0) {
          (void)global_sum(gen);              // WAR guard before t_g/u_g overwrite
          float ztr = 0.f, urow = 0.f;
          if (lane < 8) {
#pragma unroll
            for (int q = 0; q < 8; ++q) ztr += dred[q][lane];
            const float zt = al * ztr + (1.f - al) * f_zb;
            float zn = fminf(fmaxf(zt + f_yb / rho, f_lbs), f_ubs);
            const float yn = f_yb + rho * (zt - zn);
            f_zb = zn; f_yb = yn;
            urow = rho * zn - yn;
          }
          f_xa = al * f_xtl + (1.f - al) * f_xa;   // x at own 16 cols
          float ta = __shfl(ztr,  (lane & 3) * 2, 64);
          float tb = __shfl(ztr,  (lane & 3) * 2 + 1, 64);
          float ua = __shfl(urow, (lane & 3) * 2, 64);
          float ub = __shfl(urow, (lane & 3) * 2 + 1, 64);
          if (lane < 4) {
            st64(&t64[(size_t)w * 4 + lane], pk2(ta, tb));
            st64(&u64[(size_t)w * 4 + lane], pk2(ua, ub));
          }
          publish(0.f);
        }
        ++gen;
      }
      // ---- B: right = sig*x - c + A^T u; r0 = right - Kop(xt); publish z -------
      {
        gate(gen);                            // t,u producers
        float pk = 0.f, pr = 0.f;
#pragma unroll
        for (int r4 = 0; r4 < RPT / 4; ++r4) {
          const f32x4 tv = ntf4(t_g + g * RPT + r4 * 4);
          const f32x4 uv = ntf4(u_g + g * RPT + r4 * 4);
          pk += tv.x * acol[r4 * 4 + 0] + tv.y * acol[r4 * 4 + 1]
              + tv.z * acol[r4 * 4 + 2] + tv.w * acol[r4 * 4 + 3];
          pr += uv.x * acol[r4 * 4 + 0] + uv.y * acol[r4 * 4 + 1]
              + uv.z * acol[r4 * 4 + 2] + uv.w * acol[r4 * 4 + 3];
        }
        sredA[g][l] = pk; sredB[g][l] = pr;
        __syncthreads();
        if (wv == 0) {
          (void)global_sum(gen);              // WAR guard before z overwrite
          float SK = 0.f, SR = 0.f;
          if (lane < 16) {
#pragma unroll
            for (int q = 0; q < 32; ++q) { SK += sredA[q][lane]; SR += sredB[q][lane]; }
          }
          const float right = sig * f_xa - f_cs + SR;
          const float Kx = rho * SK + sig * f_xtl;
          const float r0 = right - Kx;
          f_rl = r0;
          f_zown = r0 / f_Md;
          float rzp = (lane < 16) ? r0 * f_zown : 0.f;
          rzp = sum16(rzp);
          float a0 = __shfl(f_zown, (lane & 7) * 2, 64);
          float b0 = __shfl(f_zown, (lane & 7) * 2 + 1, 64);
          if (lane < 8) st64(&z64[(size_t)w * 8 + lane], pk2(a0, b0));
          publish(rzp);
        }
        ++gen;
      }
    }
  }
  // ---------------- final: out = (al*xt + (1-al)*x) * d / gb ---------------------
  if (wv == 0 && lane < 16) {
    const float xf = al * f_xtl + (1.f - al) * f_xa;
    out[w * 16 + lane] = xf * dvec[w * 16 + lane] / gbv;
  }
}

extern "C" void kernel_launch(void* const* d_in, const int* in_sizes, int n_in,
                              void* d_out, int out_size, void* d_ws, size_t ws_size,
                              hipStream_t stream) {
  const float* A   = (const float*)d_in[0];
  const float* c   = (const float*)d_in[1];
  const float* lb  = (const float*)d_in[2];
  const float* ub  = (const float*)d_in[3];
  const float* dv  = (const float*)d_in[4];
  const float* ev  = (const float*)d_in[5];
  const float* gc  = (const float*)d_in[6];
  const float* gb  = (const float*)d_in[7];
  const float* rho = (const float*)d_in[8];
  const float* sg  = (const float*)d_in[9];
  const float* al  = (const float*)d_in[10];
  float* out = (float*)d_out;
  unsigned char* ws = (unsigned char*)d_ws;

  // zero kill + L0 banks + L1 banks (data buffers start at 49152)
  (void)hipMemsetAsync(d_ws, 0, 49152, stream);

  admm_lp_kernel<<<dim3(NWG), dim3(NT), 0, stream>>>(
      A, c, lb, ub, dv, ev, gc, gb, rho, sg, al, out, ws);
}